// Round 3
// baseline (60.011 us; speedup 1.0000x reference)
//
#include <hip/hip_runtime.h>
#include <math.h>

#define N1V    8192
#define N2V    8192
#define QB     64                 // queries per block (one per lane)
#define BLOCK  1024               // 16 waves
#define NSEG   (BLOCK / QB)       // 16 segments, one per wave
#define SEGLEN (N1V / NSEG)       // 512 points per wave
#define KEYMASK 0xFFFFFE00u       // keep 14 mantissa bits; low 9 bits = local idx
#define IDXMASK 0x000001FFu
#define FMAXV  __uint_as_float(0x7F7FFFFFu)

// ---- pre-pass: interleaved warped points (x, y, z, |s|^2) into d_ws -------
__global__ void prep_pts(const float* __restrict__ xyz1,
                         const float* __restrict__ flow1,
                         float4* __restrict__ pts)
{
    const int b = blockIdx.y;
    const int j = blockIdx.x * 256 + threadIdx.x;
    const float* x1 = xyz1 + b * 3 * N1V;
    const float* f1 = flow1 + b * 3 * N1V;
    float sx = x1[j]           + f1[j];
    float sy = x1[N1V + j]     + f1[N1V + j];
    float sz = x1[2 * N1V + j] + f1[2 * N1V + j];
    pts[b * N1V + j] = make_float4(sx, sy, sz, fmaf(sx, sx, fmaf(sy, sy, sz * sz)));
}

// ---- main: brute-force KNN-3 + IDW flow interpolation ---------------------
__global__ __launch_bounds__(BLOCK, 4)
void pointwarp_knn3_kernel(const float4* __restrict__ pts,
                           const float* __restrict__ xyz2,
                           const float* __restrict__ flow1,
                           float* __restrict__ out)
{
    __shared__ float rv[BLOCK * 3];   // exact d2 of candidates
    __shared__ int   ri[BLOCK * 3];   // global indices

    const int b    = blockIdx.y;
    const int t    = threadIdx.x;
    const int lane = t & (QB - 1);
    const int seg  = __builtin_amdgcn_readfirstlane(t >> 6);  // wave-uniform -> SGPR
    const int qi   = blockIdx.x * QB + lane;

    const float* x2 = xyz2 + b * 3 * N2V;
    const float* f1 = flow1 + b * 3 * N1V;

    const float qx = x2[qi];
    const float qy = x2[N2V + qi];
    const float qz = x2[2 * N2V + qi];
    const float cq  = fmaf(qx, qx, fmaf(qy, qy, qz * qz));
    const float qxn = -2.0f * qx;
    const float qyn = -2.0f * qy;
    const float qzn = -2.0f * qz;

    // ---- scan own segment; points come in via scalar loads (wave-uniform) --
    const float4* __restrict__ p = pts + b * N1V + seg * SEGLEN;

    float c0 = FMAXV, c1 = FMAXV, c2 = FMAXV;
    #pragma unroll 8
    for (int i = 0; i < SEGLEN; ++i) {
        float4 s = p[i];               // uniform addr -> s_load, no LDS/VMEM cost on VALU
        float d2 = fmaf(s.x, qxn, fmaf(s.y, qyn, fmaf(s.z, qzn, s.w + cq)));
        d2 = fmaxf(d2, 0.0f);
        float kf = __uint_as_float((__float_as_uint(d2) & KEYMASK) | (unsigned)i);
        c2 = __builtin_amdgcn_fmed3f(c1, c2, kf);
        c1 = __builtin_amdgcn_fmed3f(c0, c1, kf);
        c0 = fminf(c0, kf);
    }

    // ---- exact d2 for the 3 candidates (per-thread scattered loads, L2-hit)
    const int base = seg * SEGLEN;
    int g0 = base + (int)(__float_as_uint(c0) & IDXMASK);
    int g1 = base + (int)(__float_as_uint(c1) & IDXMASK);
    int g2 = base + (int)(__float_as_uint(c2) & IDXMASK);
    float4 p0 = pts[b * N1V + g0];
    float4 p1 = pts[b * N1V + g1];
    float4 p2 = pts[b * N1V + g2];
    float dx, dy, dz;
    dx = p0.x - qx; dy = p0.y - qy; dz = p0.z - qz;
    float e0 = fmaf(dx, dx, fmaf(dy, dy, dz * dz));
    dx = p1.x - qx; dy = p1.y - qy; dz = p1.z - qz;
    float e1 = fmaf(dx, dx, fmaf(dy, dy, dz * dz));
    dx = p2.x - qx; dy = p2.y - qy; dz = p2.z - qz;
    float e2 = fmaf(dx, dx, fmaf(dy, dy, dz * dz));

    rv[t * 3 + 0] = e0; ri[t * 3 + 0] = g0;
    rv[t * 3 + 1] = e1; ri[t * 3 + 1] = g1;
    rv[t * 3 + 2] = e2; ri[t * 3 + 2] = g2;
    __syncthreads();

    // ---- merge 16 segment-triples per query, exact values, branchy (t<64) --
    if (t < QB) {
        float b0 = FMAXV, b1 = FMAXV, b2 = FMAXV;
        int   j0 = 0, j1 = 0, j2 = 0;
        // segments in ascending order; within a segment candidates are sorted
        // with lowest-index-on-tie, so strict '<' reproduces top_k tie-break.
        for (int s = 0; s < NSEG; ++s) {
            int u = (s * QB + t) * 3;
            #pragma unroll
            for (int m = 0; m < 3; ++m) {
                float d = rv[u + m];
                int   j = ri[u + m];
                if (d < b2) {
                    if (d < b1) {
                        b2 = b1; j2 = j1;
                        if (d < b0) { b1 = b0; j1 = j0; b0 = d; j0 = j; }
                        else        { b1 = d;  j1 = j; }
                    } else {
                        b2 = d; j2 = j;
                    }
                }
            }
        }

        float d0 = fmaxf(sqrtf(fmaxf(b0, 0.0f)), 1e-10f);
        float d1 = fmaxf(sqrtf(fmaxf(b1, 0.0f)), 1e-10f);
        float d2 = fmaxf(sqrtf(fmaxf(b2, 0.0f)), 1e-10f);
        float i0 = 1.0f / d0, i1 = 1.0f / d1, i2 = 1.0f / d2;
        float wsum = i0 + i1 + i2;
        float w0 = i0 / wsum, w1 = i1 / wsum, w2 = i2 / wsum;

        float fxo = w0 * f1[j0]           + w1 * f1[j1]           + w2 * f1[j2];
        float fyo = w0 * f1[N1V + j0]     + w1 * f1[N1V + j1]     + w2 * f1[N1V + j2];
        float fzo = w0 * f1[2 * N1V + j0] + w1 * f1[2 * N1V + j1] + w2 * f1[2 * N1V + j2];

        float* ob = out + b * 3 * N2V;
        ob[qi]           = qx - fxo;
        ob[N2V + qi]     = qy - fyo;
        ob[2 * N2V + qi] = qz - fzo;
    }
}

extern "C" void kernel_launch(void* const* d_in, const int* in_sizes, int n_in,
                              void* d_out, int out_size, void* d_ws, size_t ws_size,
                              hipStream_t stream)
{
    const float* xyz1  = (const float*)d_in[0];
    const float* xyz2  = (const float*)d_in[1];
    const float* flow1 = (const float*)d_in[2];
    float* out = (float*)d_out;
    const int B = in_sizes[0] / (3 * N1V);

    float4* pts = (float4*)d_ws;   // B * N1V * 16 bytes = 256 KB for B=2

    dim3 pgrid(N1V / 256, B);
    prep_pts<<<pgrid, 256, 0, stream>>>(xyz1, flow1, pts);

    dim3 grid(N2V / QB, B);
    dim3 block(BLOCK);
    pointwarp_knn3_kernel<<<grid, block, 0, stream>>>(pts, xyz2, flow1, out);
}

// Round 4
// 41.293 us; speedup vs baseline: 1.4533x; 1.4533x over previous
//
#include <hip/hip_runtime.h>
#include <math.h>

#define N1V    8192
#define N2V    8192
#define BLOCK  1024               // 16 waves
#define NW     16                 // waves per block
#define QPL    4                  // queries per lane
#define QPB    (64 * QPL)         // 256 queries per block
#define NQUART 4                  // N1 split across blockIdx.y
#define QUART  (N1V / NQUART)     // 2048 points staged per block
#define SEGLEN (QUART / NW)       // 128 points scanned per wave
#define KEYMASK 0xFFFFFF80u       // keep 16 mantissa bits; low 7 = local idx
#define IDXMASK 0x0000007Fu
#define FMAXV  __uint_as_float(0x7F7FFFFFu)
#define MPAD   13                 // odd stride -> conflict-free merge buffer

// ---- pass 1: per-(block, quarter) top-3 with exact d2 ---------------------
__global__ __launch_bounds__(BLOCK, 1)
void knn_part(const float* __restrict__ xyz1,
              const float* __restrict__ xyz2,
              const float* __restrict__ flow1,
              float2* __restrict__ ws)
{
    __shared__ float4 sPts[QUART];        // 32 KB
    __shared__ float  rv[BLOCK * MPAD];   // 52 KB (12 used per thread)
    __shared__ int    ri[BLOCK * MPAD];   // 52 KB

    const int b     = blockIdx.z;
    const int qu    = blockIdx.y;
    const int qbase = blockIdx.x * QPB;
    const int t     = threadIdx.x;
    const int lane  = t & 63;
    const int wv    = t >> 6;

    const float* x1 = xyz1 + b * 3 * N1V + qu * QUART;
    const float* f1 = flow1 + b * 3 * N1V + qu * QUART;
    const float* x2 = xyz2 + b * 3 * N2V;

    // stage this block's quarter of warped source points
    for (int j = t; j < QUART; j += BLOCK) {
        float sx = x1[j]           + f1[j];
        float sy = x1[N1V + j]     + f1[N1V + j];
        float sz = x1[2 * N1V + j] + f1[2 * N1V + j];
        sPts[j] = make_float4(sx, sy, sz, fmaf(sx, sx, fmaf(sy, sy, sz * sz)));
    }

    // 4 queries per lane
    float qx[QPL], qy[QPL], qz[QPL], ax[QPL], ay[QPL], az[QPL];
    #pragma unroll
    for (int k = 0; k < QPL; ++k) {
        int qi = qbase + k * 64 + lane;
        qx[k] = x2[qi];
        qy[k] = x2[N2V + qi];
        qz[k] = x2[2 * N2V + qi];
        ax[k] = -2.0f * qx[k];
        ay[k] = -2.0f * qy[k];
        az[k] = -2.0f * qz[k];
    }

    __syncthreads();

    // scan: d' = |s|^2 - 2 q.s  (same ordering as d2 per fixed query)
    float c0[QPL], c1[QPL], c2[QPL];
    #pragma unroll
    for (int k = 0; k < QPL; ++k) { c0[k] = FMAXV; c1[k] = FMAXV; c2[k] = FMAXV; }

    const int s0 = wv * SEGLEN;
    #pragma unroll 8
    for (int i = 0; i < SEGLEN; ++i) {
        float4 s = sPts[s0 + i];   // wave-uniform -> LDS broadcast
        #pragma unroll
        for (int k = 0; k < QPL; ++k) {
            float d  = fmaf(s.x, ax[k], fmaf(s.y, ay[k], fmaf(s.z, az[k], s.w)));
            float kf = __uint_as_float((__float_as_uint(d) & KEYMASK) | (unsigned)i);
            c2[k] = __builtin_amdgcn_fmed3f(c1[k], c2[k], kf);
            c1[k] = __builtin_amdgcn_fmed3f(c0[k], c1[k], kf);
            c0[k] = fminf(c0[k], kf);
        }
    }

    // exact d2 for each candidate (diff form, from LDS), stash for merge
    #pragma unroll
    for (int k = 0; k < QPL; ++k) {
        float cc[3] = { c0[k], c1[k], c2[k] };
        #pragma unroll
        for (int m = 0; m < 3; ++m) {
            int li = (int)(__float_as_uint(cc[m]) & IDXMASK) + s0;
            float4 p = sPts[li];
            float dx = p.x - qx[k], dy = p.y - qy[k], dz = p.z - qz[k];
            rv[t * MPAD + k * 3 + m] = fmaf(dx, dx, fmaf(dy, dy, dz * dz));
            ri[t * MPAD + k * 3 + m] = qu * QUART + li;
        }
    }
    __syncthreads();

    // merge 16 wave-triples per query (exact values, ascending wave order)
    if (t < QPB) {
        const int ml = t & 63;      // lane that owned this query
        const int mk = t >> 6;      // its query slot
        float b0 = FMAXV, b1 = FMAXV, b2 = FMAXV;
        int   j0 = 0, j1 = 0, j2 = 0;
        for (int w = 0; w < NW; ++w) {
            int u = (w * 64 + ml) * MPAD + mk * 3;
            #pragma unroll
            for (int m = 0; m < 3; ++m) {
                float d = rv[u + m];
                int   j = ri[u + m];
                if (d < b2) {
                    if (d < b1) {
                        b2 = b1; j2 = j1;
                        if (d < b0) { b1 = b0; j1 = j0; b0 = d; j0 = j; }
                        else        { b1 = d;  j1 = j; }
                    } else {
                        b2 = d; j2 = j;
                    }
                }
            }
        }
        int qi = qbase + t;
        float2* wq = ws + ((size_t)(b * NQUART + qu) * N2V + qi) * 3;
        wq[0] = make_float2(b0, __int_as_float(j0));
        wq[1] = make_float2(b1, __int_as_float(j1));
        wq[2] = make_float2(b2, __int_as_float(j2));
    }
}

// ---- pass 2: merge 4 quarters, weights, flow gather, output ---------------
__global__ __launch_bounds__(256)
void knn_merge(const float* __restrict__ xyz2,
               const float* __restrict__ flow1,
               const float2* __restrict__ ws,
               float* __restrict__ out)
{
    const int gid = blockIdx.x * 256 + threadIdx.x;
    const int b   = gid / N2V;
    const int qi  = gid - b * N2V;

    float b0 = FMAXV, b1 = FMAXV, b2 = FMAXV;
    int   j0 = 0, j1 = 0, j2 = 0;
    for (int qu = 0; qu < NQUART; ++qu) {
        const float2* wq = ws + ((size_t)(b * NQUART + qu) * N2V + qi) * 3;
        #pragma unroll
        for (int m = 0; m < 3; ++m) {
            float2 c = wq[m];
            float d = c.x;
            int   j = __float_as_int(c.y);
            if (d < b2) {
                if (d < b1) {
                    b2 = b1; j2 = j1;
                    if (d < b0) { b1 = b0; j1 = j0; b0 = d; j0 = j; }
                    else        { b1 = d;  j1 = j; }
                } else {
                    b2 = d; j2 = j;
                }
            }
        }
    }

    float d0 = fmaxf(sqrtf(fmaxf(b0, 0.0f)), 1e-10f);
    float d1 = fmaxf(sqrtf(fmaxf(b1, 0.0f)), 1e-10f);
    float d2 = fmaxf(sqrtf(fmaxf(b2, 0.0f)), 1e-10f);
    float i0 = 1.0f / d0, i1 = 1.0f / d1, i2 = 1.0f / d2;
    float wsum = i0 + i1 + i2;
    float w0 = i0 / wsum, w1 = i1 / wsum, w2 = i2 / wsum;

    const float* f1 = flow1 + b * 3 * N1V;
    const float* x2 = xyz2 + b * 3 * N2V;
    float fxo = w0 * f1[j0]           + w1 * f1[j1]           + w2 * f1[j2];
    float fyo = w0 * f1[N1V + j0]     + w1 * f1[N1V + j1]     + w2 * f1[N1V + j2];
    float fzo = w0 * f1[2 * N1V + j0] + w1 * f1[2 * N1V + j1] + w2 * f1[2 * N1V + j2];

    float* ob = out + b * 3 * N2V;
    ob[qi]           = x2[qi]           - fxo;
    ob[N2V + qi]     = x2[N2V + qi]     - fyo;
    ob[2 * N2V + qi] = x2[2 * N2V + qi] - fzo;
}

extern "C" void kernel_launch(void* const* d_in, const int* in_sizes, int n_in,
                              void* d_out, int out_size, void* d_ws, size_t ws_size,
                              hipStream_t stream)
{
    const float* xyz1  = (const float*)d_in[0];
    const float* xyz2  = (const float*)d_in[1];
    const float* flow1 = (const float*)d_in[2];
    float* out = (float*)d_out;
    const int B = in_sizes[0] / (3 * N1V);

    float2* ws = (float2*)d_ws;   // B * NQUART * N2V * 3 * 8 B = 1.5 MB @ B=2

    dim3 grid(N2V / QPB, NQUART, B);    // (32, 4, B)
    knn_part<<<grid, BLOCK, 0, stream>>>(xyz1, xyz2, flow1, ws);

    knn_merge<<<(B * N2V) / 256, 256, 0, stream>>>(xyz2, flow1, ws, out);
}

// Round 5
// 38.583 us; speedup vs baseline: 1.5554x; 1.0702x over previous
//
#include <hip/hip_runtime.h>
#include <math.h>

#define N1V    8192
#define N2V    8192
#define BLOCK  1024               // 16 waves
#define NW     16
#define NQUART 4                  // N1 split across blockIdx.y
#define QUART  (N1V / NQUART)     // 2048 points staged per block
#define TILES  (QUART / 16)       // 128 MFMA tiles per scan
#define QPW    16                 // queries per wave (MFMA N dim)
#define QPB    (NW * QPW)         // 256 queries per block
#define KEYMASK 0xFFFFFE00u      // keep 14 mantissa bits; low 9 = local idx
#define LOCMASK 0x1FFu
#define FMAXV  __uint_as_float(0x7F7FFFFFu)

typedef __attribute__((ext_vector_type(8))) short short8;
typedef __attribute__((ext_vector_type(4))) float float4v;

// split f32 into bf16 hi (truncate) + bf16 lo (truncate of remainder)
__device__ __forceinline__ void bsplit(float x, unsigned short& h, unsigned short& l) {
    unsigned hb = __float_as_uint(x) & 0xFFFF0000u;
    h = (unsigned short)(hb >> 16);
    float lo = x - __uint_as_float(hb);
    l = (unsigned short)(__float_as_uint(lo) >> 16);
}

// K-slot schedule (A = point rows, B = query cols), d' = |s|^2 - 2 q.s :
//  k0-2: s_h[c]   * -2q_h[c]    k3-5: s_l[c] * -2q_h[c]
//  k6-7: s_h[x,y] * -2q_l[x,y]  k8:   s_h[z] * -2q_l[z]
//  k9:   w_h * 1                k10:  w_l * 1          k11-31: 0
__global__ __launch_bounds__(BLOCK, 1)
void knn_part(const float* __restrict__ xyz1,
              const float* __restrict__ xyz2,
              const float* __restrict__ flow1,
              float2* __restrict__ ws)
{
    __shared__ unsigned short sA[TILES * 256 + 8];  // [tile][g2][pt16][8] + zero blk (64KB)
    __shared__ float4 sPts[QUART];                  // exact f32 points (32KB)
    __shared__ float  sScr[NW][64 * 3];             // per-wave packed top-3 (12KB)

    const int b     = blockIdx.z;
    const int qu    = blockIdx.y;
    const int qbase = blockIdx.x * QPB;
    const int t     = threadIdx.x;
    const int lane  = t & 63;
    const int w     = t >> 6;

    const float* x1 = xyz1 + b * 3 * N1V + qu * QUART;
    const float* f1 = flow1 + b * 3 * N1V + qu * QUART;
    const float* x2 = xyz2 + b * 3 * N2V;

    // ---- stage: exact f32 points + pre-split bf16 A-fragments -------------
    for (int j = t; j < QUART; j += BLOCK) {
        float sx = x1[j]           + f1[j];
        float sy = x1[N1V + j]     + f1[N1V + j];
        float sz = x1[2*N1V + j]   + f1[2*N1V + j];
        float wv = fmaf(sx, sx, fmaf(sy, sy, sz * sz));
        sPts[j] = make_float4(sx, sy, sz, wv);
        unsigned short xh,xl,yh,yl,zh,zl,wh,wl;
        bsplit(sx, xh, xl); bsplit(sy, yh, yl);
        bsplit(sz, zh, zl); bsplit(wv, wh, wl);
        unsigned base = (unsigned)(j >> 4) * 256u + (unsigned)(j & 15) * 8u;
        *(uint4*)&sA[base] = make_uint4(
            (unsigned)xh | ((unsigned)yh << 16),
            (unsigned)zh | ((unsigned)xl << 16),
            (unsigned)yl | ((unsigned)zl << 16),
            (unsigned)xh | ((unsigned)yh << 16));
        *(uint4*)&sA[base + 128] = make_uint4(
            (unsigned)zh | ((unsigned)wh << 16),
            (unsigned)wl, 0u, 0u);
    }
    if (t < 8) sA[TILES * 256 + t] = 0;   // zero block for lanes 32-63

    // ---- B fragment: this wave's 16 queries, built once -------------------
    const int col = lane & 15;
    const int g   = lane >> 4;
    const int qi  = qbase + w * QPW + col;
    const float qx = x2[qi], qy = x2[N2V + qi], qz = x2[2*N2V + qi];

    unsigned short qxh,qxl,qyh,qyl,qzh,qzl;
    bsplit(-2.0f * qx, qxh, qxl);
    bsplit(-2.0f * qy, qyh, qyl);
    bsplit(-2.0f * qz, qzh, qzl);
    short8 bf = {0,0,0,0,0,0,0,0};
    if (g == 0) {
        bf[0]=(short)qxh; bf[1]=(short)qyh; bf[2]=(short)qzh;
        bf[3]=(short)qxh; bf[4]=(short)qyh; bf[5]=(short)qzh;
        bf[6]=(short)qxl; bf[7]=(short)qyl;
    } else if (g == 1) {
        bf[0]=(short)qzl; bf[1]=(short)0x3F80; bf[2]=(short)0x3F80;  // 1.0 bf16
    }

    const int aoff = (lane < 32) ? (g & 1) * 128 + col * 8 : TILES * 256;
    const int ainc = (lane < 32) ? 256 : 0;

    __syncthreads();

    // ---- MFMA scan: selection is the only per-pair VALU work --------------
    float c0 = FMAXV, c1 = FMAXV, c2 = FMAXV;
    const unsigned short* ap = &sA[aoff];
    const float4v zc = {0.0f, 0.0f, 0.0f, 0.0f};
    #pragma unroll 4
    for (int tl = 0; tl < TILES; ++tl) {
        short8 a = *(const short8*)ap;
        ap += ainc;
        float4v acc = __builtin_amdgcn_mfma_f32_16x16x32_bf16(a, bf, zc, 0, 0, 0);
        #pragma unroll
        for (int j = 0; j < 4; ++j) {
            float kf = __uint_as_float((__float_as_uint(acc[j]) & KEYMASK)
                                       | (unsigned)(tl * 4 + j));
            c2 = __builtin_amdgcn_fmed3f(c1, c2, kf);
            c1 = __builtin_amdgcn_fmed3f(c0, c1, kf);
            c0 = fminf(c0, kf);
        }
    }

    // ---- exchange 4 lane-groups' triples, exact-refine 12 candidates ------
    sScr[w][lane*3+0] = c0; sScr[w][lane*3+1] = c1; sScr[w][lane*3+2] = c2;
    __syncthreads();

    if (lane < 16) {
        float e0 = FMAXV, e1 = FMAXV, e2 = FMAXV;
        int   i0 = 0, i1 = 0, i2 = 0;
        #pragma unroll
        for (int gg = 0; gg < 4; ++gg) {
            #pragma unroll
            for (int m = 0; m < 3; ++m) {
                unsigned key = __float_as_uint(sScr[w][(gg*16 + lane)*3 + m]);
                int local = (int)(key & LOCMASK);
                int pidx  = ((local >> 2) << 4) + gg * 4 + (local & 3);
                float4 p = sPts[pidx];
                float dx = p.x - qx, dy = p.y - qy, dz = p.z - qz;
                float d  = fmaf(dx, dx, fmaf(dy, dy, dz * dz));
                if (d < e2) {
                    if (d < e1) {
                        e2 = e1; i2 = i1;
                        if (d < e0) { e1 = e0; i1 = i0; e0 = d; i0 = pidx; }
                        else        { e1 = d;  i1 = pidx; }
                    } else { e2 = d; i2 = pidx; }
                }
            }
        }
        float2* wq = ws + ((size_t)(b * NQUART + qu) * N2V + qi) * 3;
        wq[0] = make_float2(e0, __int_as_float(qu * QUART + i0));
        wq[1] = make_float2(e1, __int_as_float(qu * QUART + i1));
        wq[2] = make_float2(e2, __int_as_float(qu * QUART + i2));
    }
}

// ---- pass 2: merge 4 quarters, weights, flow gather, output ---------------
__global__ __launch_bounds__(256)
void knn_merge(const float* __restrict__ xyz2,
               const float* __restrict__ flow1,
               const float2* __restrict__ ws,
               float* __restrict__ out)
{
    const int gid = blockIdx.x * 256 + threadIdx.x;
    const int b   = gid / N2V;
    const int qi  = gid - b * N2V;

    float b0 = FMAXV, b1 = FMAXV, b2 = FMAXV;
    int   j0 = 0, j1 = 0, j2 = 0;
    for (int qu = 0; qu < NQUART; ++qu) {
        const float2* wq = ws + ((size_t)(b * NQUART + qu) * N2V + qi) * 3;
        #pragma unroll
        for (int m = 0; m < 3; ++m) {
            float2 c = wq[m];
            float d = c.x;
            int   j = __float_as_int(c.y);
            if (d < b2) {
                if (d < b1) {
                    b2 = b1; j2 = j1;
                    if (d < b0) { b1 = b0; j1 = j0; b0 = d; j0 = j; }
                    else        { b1 = d;  j1 = j; }
                } else { b2 = d; j2 = j; }
            }
        }
    }

    float d0 = fmaxf(sqrtf(fmaxf(b0, 0.0f)), 1e-10f);
    float d1 = fmaxf(sqrtf(fmaxf(b1, 0.0f)), 1e-10f);
    float d2 = fmaxf(sqrtf(fmaxf(b2, 0.0f)), 1e-10f);
    float i0 = 1.0f / d0, i1 = 1.0f / d1, i2 = 1.0f / d2;
    float wsum = i0 + i1 + i2;
    float w0 = i0 / wsum, w1 = i1 / wsum, w2 = i2 / wsum;

    const float* f1 = flow1 + b * 3 * N1V;
    const float* x2 = xyz2 + b * 3 * N2V;
    float fxo = w0 * f1[j0]           + w1 * f1[j1]           + w2 * f1[j2];
    float fyo = w0 * f1[N1V + j0]     + w1 * f1[N1V + j1]     + w2 * f1[N1V + j2];
    float fzo = w0 * f1[2*N1V + j0]   + w1 * f1[2*N1V + j1]   + w2 * f1[2*N1V + j2];

    float* ob = out + b * 3 * N2V;
    ob[qi]           = x2[qi]           - fxo;
    ob[N2V + qi]     = x2[N2V + qi]     - fyo;
    ob[2*N2V + qi]   = x2[2*N2V + qi]   - fzo;
}

extern "C" void kernel_launch(void* const* d_in, const int* in_sizes, int n_in,
                              void* d_out, int out_size, void* d_ws, size_t ws_size,
                              hipStream_t stream)
{
    const float* xyz1  = (const float*)d_in[0];
    const float* xyz2  = (const float*)d_in[1];
    const float* flow1 = (const float*)d_in[2];
    float* out = (float*)d_out;
    const int B = in_sizes[0] / (3 * N1V);

    float2* ws = (float2*)d_ws;   // B * NQUART * N2V * 3 * 8 B = 1.5 MB @ B=2

    dim3 grid(N2V / QPB, NQUART, B);    // (32, 4, B) = 256 blocks
    knn_part<<<grid, BLOCK, 0, stream>>>(xyz1, xyz2, flow1, ws);

    knn_merge<<<(B * N2V) / 256, 256, 0, stream>>>(xyz2, flow1, ws, out);
}

// Round 6
// 27.809 us; speedup vs baseline: 2.1579x; 1.3874x over previous
//
#include <hip/hip_runtime.h>
#include <math.h>

#define N1V    8192
#define N2V    8192
#define BLOCK  1024               // 16 waves
#define NW     16
#define NOCT   8                  // N1 split into eighths across blockIdx.y
#define OCT    (N1V / NOCT)       // 1024 points staged per block
#define TILES  (OCT / 16)         // 64 MFMA tiles per scan
#define QPW    16                 // queries per wave (MFMA N dim)
#define QPB    (NW * QPW)         // 256 queries per block
#define TKEYMASK 0xFFFFFFC0u      // tile key: low 6 bits = tile id
#define TMASK    0x3Fu
#define PKEYMASK 0xFFFFFC00u      // point key: low 10 bits = local point idx
#define PMASK    0x3FFu
#define FMAXV  __uint_as_float(0x7F7FFFFFu)

typedef __attribute__((ext_vector_type(8))) short short8;
typedef __attribute__((ext_vector_type(4))) float float4v;

// split f32 into bf16 hi (truncate) + bf16 lo (truncate of remainder)
__device__ __forceinline__ void bsplit(float x, unsigned short& h, unsigned short& l) {
    unsigned hb = __float_as_uint(x) & 0xFFFF0000u;
    h = (unsigned short)(hb >> 16);
    float lo = x - __uint_as_float(hb);
    l = (unsigned short)(__float_as_uint(lo) >> 16);
}

// K-slot schedule (A = point rows, B = query cols), d' = |s|^2 - 2 q.s :
//  k0-2: s_h * -2q_h   k3-5: s_l * -2q_h   k6-8: s_h * -2q_l
//  k9: w_h * 1   k10: w_l * 1   k11-31: B is zero -> A content irrelevant
__global__ __launch_bounds__(BLOCK, 8)
void knn_part(const float* __restrict__ xyz1,
              const float* __restrict__ xyz2,
              const float* __restrict__ flow1,
              float2* __restrict__ ws)
{
    __shared__ __align__(16) unsigned short sA[TILES * 256]; // 32 KB bf16 A-frags
    __shared__ float4 sPts[OCT];                             // 16 KB exact points
    __shared__ float  sCand[NW][64 * 3];                     // 12 KB packed top-3

    const int b     = blockIdx.z;
    const int oc    = blockIdx.y;
    const int qbase = blockIdx.x * QPB;
    const int t     = threadIdx.x;
    const int lane  = t & 63;
    const int w     = t >> 6;

    const float* x1 = xyz1 + b * 3 * N1V + oc * OCT;
    const float* f1 = flow1 + b * 3 * N1V + oc * OCT;
    const float* x2 = xyz2 + b * 3 * N2V;

    // ---- stage: exact f32 points + pre-split bf16 A-fragments (1 pt/thread)
    {
        const int j = t;
        float sx = x1[j]           + f1[j];
        float sy = x1[N1V + j]     + f1[N1V + j];
        float sz = x1[2*N1V + j]   + f1[2*N1V + j];
        float wv = fmaf(sx, sx, fmaf(sy, sy, sz * sz));
        sPts[j] = make_float4(sx, sy, sz, wv);
        unsigned short xh,xl,yh,yl,zh,zl,wh,wl;
        bsplit(sx, xh, xl); bsplit(sy, yh, yl);
        bsplit(sz, zh, zl); bsplit(wv, wh, wl);
        unsigned base = (unsigned)(j >> 4) * 256u + (unsigned)(j & 15) * 8u;
        *(uint4*)&sA[base] = make_uint4(
            (unsigned)xh | ((unsigned)yh << 16),
            (unsigned)zh | ((unsigned)xl << 16),
            (unsigned)yl | ((unsigned)zl << 16),
            (unsigned)xh | ((unsigned)yh << 16));
        *(uint4*)&sA[base + 128] = make_uint4(
            (unsigned)zh | ((unsigned)wh << 16),
            (unsigned)wl, 0u, 0u);
    }

    // ---- B fragment: this wave's 16 queries ---------------------------------
    const int col = lane & 15;
    const int g   = lane >> 4;
    const int qi  = qbase + w * QPW + col;
    const float qx = x2[qi], qy = x2[N2V + qi], qz = x2[2*N2V + qi];

    unsigned short qxh,qxl,qyh,qyl,qzh,qzl;
    bsplit(-2.0f * qx, qxh, qxl);
    bsplit(-2.0f * qy, qyh, qyl);
    bsplit(-2.0f * qz, qzh, qzl);
    short8 bf = {0,0,0,0,0,0,0,0};
    if (g == 0) {
        bf[0]=(short)qxh; bf[1]=(short)qyh; bf[2]=(short)qzh;
        bf[3]=(short)qxh; bf[4]=(short)qyh; bf[5]=(short)qzh;
        bf[6]=(short)qxl; bf[7]=(short)qyl;
    } else if (g == 1) {
        bf[0]=(short)qzl; bf[1]=(short)0x3F80; bf[2]=(short)0x3F80;  // 1.0 bf16
    }

    // all lanes read real A data; lanes with k>=16 multiply zero B slots
    const unsigned short* ap = &sA[(unsigned)(((g & 1) * 128) + col * 8)];

    __syncthreads();

    // ---- MFMA scan with tournament selection: 7 VALU per 4 pairs ------------
    float c0 = FMAXV, c1 = FMAXV, c2 = FMAXV;
    const float4v zc = {0.0f, 0.0f, 0.0f, 0.0f};
    #pragma unroll
    for (int tl = 0; tl < TILES; ++tl) {
        short8 a = *(const short8*)(ap + tl * 256);     // offset-imm ds_read_b128
        float4v acc = __builtin_amdgcn_mfma_f32_16x16x32_bf16(a, bf, zc, 0, 0, 0);
        float m  = fminf(fminf(acc[0], acc[1]), fminf(acc[2], acc[3]));
        float kf = __uint_as_float((__float_as_uint(m) & TKEYMASK) | (unsigned)tl);
        c2 = __builtin_amdgcn_fmed3f(c1, c2, kf);
        c1 = __builtin_amdgcn_fmed3f(c0, c1, kf);
        c0 = fminf(c0, kf);
    }

    // ---- refine: expand 3 winning tiles (4 pts each) with exact f32 d2 ------
    float e0 = FMAXV, e1 = FMAXV, e2 = FMAXV;
    const int g4 = g * 4;
    #pragma unroll
    for (int m = 0; m < 3; ++m) {
        float km = (m == 0) ? c0 : (m == 1) ? c1 : c2;
        int base = ((int)(__float_as_uint(km) & TMASK)) * 16 + g4;
        #pragma unroll
        for (int p = 0; p < 4; ++p) {
            float4 P = sPts[base + p];
            float dx = P.x - qx, dy = P.y - qy, dz = P.z - qz;
            float d  = fmaf(dx, dx, fmaf(dy, dy, dz * dz));
            float pk = __uint_as_float((__float_as_uint(d) & PKEYMASK)
                                       | (unsigned)(base + p));
            e2 = __builtin_amdgcn_fmed3f(e1, e2, pk);
            e1 = __builtin_amdgcn_fmed3f(e0, e1, pk);
            e0 = fminf(e0, pk);
        }
    }

    // ---- within-wave exchange (DS ops are in-order per wave) ----------------
    sCand[w][lane*3 + 0] = e0;
    sCand[w][lane*3 + 1] = e1;
    sCand[w][lane*3 + 2] = e2;

    if (lane < 16) {
        float b0 = FMAXV, b1 = FMAXV, b2 = FMAXV;
        #pragma unroll
        for (int gg = 0; gg < 4; ++gg) {
            #pragma unroll
            for (int m = 0; m < 3; ++m) {
                float pk = sCand[w][(gg*16 + lane)*3 + m];
                b2 = __builtin_amdgcn_fmed3f(b1, b2, pk);
                b1 = __builtin_amdgcn_fmed3f(b0, b1, pk);
                b0 = fminf(b0, pk);
            }
        }
        float2* wq = ws + ((size_t)(b * NOCT + oc) * N2V + qi) * 3;
        wq[0] = make_float2(__uint_as_float(__float_as_uint(b0) & PKEYMASK),
                            __int_as_float(oc * OCT + (int)(__float_as_uint(b0) & PMASK)));
        wq[1] = make_float2(__uint_as_float(__float_as_uint(b1) & PKEYMASK),
                            __int_as_float(oc * OCT + (int)(__float_as_uint(b1) & PMASK)));
        wq[2] = make_float2(__uint_as_float(__float_as_uint(b2) & PKEYMASK),
                            __int_as_float(oc * OCT + (int)(__float_as_uint(b2) & PMASK)));
    }
}

// ---- pass 2: merge 8 eighths, weights, flow gather, output -----------------
__global__ __launch_bounds__(256)
void knn_merge(const float* __restrict__ xyz2,
               const float* __restrict__ flow1,
               const float2* __restrict__ ws,
               float* __restrict__ out)
{
    const int gid = blockIdx.x * 256 + threadIdx.x;
    const int b   = gid / N2V;
    const int qi  = gid - b * N2V;

    float b0 = FMAXV, b1 = FMAXV, b2 = FMAXV;
    int   j0 = 0, j1 = 0, j2 = 0;
    for (int oc = 0; oc < NOCT; ++oc) {
        const float2* wq = ws + ((size_t)(b * NOCT + oc) * N2V + qi) * 3;
        #pragma unroll
        for (int m = 0; m < 3; ++m) {
            float2 c = wq[m];
            float d = c.x;
            int   j = __float_as_int(c.y);
            if (d < b2) {
                if (d < b1) {
                    b2 = b1; j2 = j1;
                    if (d < b0) { b1 = b0; j1 = j0; b0 = d; j0 = j; }
                    else        { b1 = d;  j1 = j; }
                } else { b2 = d; j2 = j; }
            }
        }
    }

    float d0 = fmaxf(sqrtf(fmaxf(b0, 0.0f)), 1e-10f);
    float d1 = fmaxf(sqrtf(fmaxf(b1, 0.0f)), 1e-10f);
    float d2 = fmaxf(sqrtf(fmaxf(b2, 0.0f)), 1e-10f);
    float i0 = 1.0f / d0, i1 = 1.0f / d1, i2 = 1.0f / d2;
    float wsum = i0 + i1 + i2;
    float w0 = i0 / wsum, w1 = i1 / wsum, w2 = i2 / wsum;

    const float* f1 = flow1 + b * 3 * N1V;
    const float* x2 = xyz2 + b * 3 * N2V;
    float fxo = w0 * f1[j0]         + w1 * f1[j1]         + w2 * f1[j2];
    float fyo = w0 * f1[N1V + j0]   + w1 * f1[N1V + j1]   + w2 * f1[N1V + j2];
    float fzo = w0 * f1[2*N1V + j0] + w1 * f1[2*N1V + j1] + w2 * f1[2*N1V + j2];

    float* ob = out + b * 3 * N2V;
    ob[qi]         = x2[qi]         - fxo;
    ob[N2V + qi]   = x2[N2V + qi]   - fyo;
    ob[2*N2V + qi] = x2[2*N2V + qi] - fzo;
}

extern "C" void kernel_launch(void* const* d_in, const int* in_sizes, int n_in,
                              void* d_out, int out_size, void* d_ws, size_t ws_size,
                              hipStream_t stream)
{
    const float* xyz1  = (const float*)d_in[0];
    const float* xyz2  = (const float*)d_in[1];
    const float* flow1 = (const float*)d_in[2];
    float* out = (float*)d_out;
    const int B = in_sizes[0] / (3 * N1V);

    float2* ws = (float2*)d_ws;   // B * NOCT * N2V * 3 * 8 B = 3.1 MB @ B=2

    dim3 grid(N2V / QPB, NOCT, B);    // (32, 8, B) = 512 blocks, 2 blocks/CU
    knn_part<<<grid, BLOCK, 0, stream>>>(xyz1, xyz2, flow1, ws);

    knn_merge<<<(B * N2V) / 256, 256, 0, stream>>>(xyz2, flow1, ws, out);
}